// Round 12
// baseline (181.458 us; speedup 1.0000x reference)
//
#include <hip/hip_runtime.h>
#include <hip/hip_bf16.h>
#include <math.h>

typedef __attribute__((ext_vector_type(8))) __bf16 bf16x8;
typedef __attribute__((ext_vector_type(4))) float f32x4;

#define NTOK 8192
#define DIN 1024
#define DOUT 1024
#define KAUG 4096
#define SEH 32

#define BK 64
#define NKT (KAUG / BK)  // 64 K-tiles, no split-K

static __device__ __forceinline__ unsigned short f2bf(float f) {
  union { float f; unsigned u; } v; v.f = f;
  unsigned r = (v.u + 0x7FFFu + ((v.u >> 16) & 1u)) >> 16;
  return (unsigned short)r;
}

// Merged prep: build_aaug (32768 blocks) + pack_w (4096) + pack_se (256).
__global__ __launch_bounds__(256) void prep(const float* __restrict__ x,
                                            const float* __restrict__ bw,
                                            const float* __restrict__ sw,
                                            const float* __restrict__ w1,
                                            const float* __restrict__ w2,
                                            ushort* __restrict__ Aaug,
                                            ushort* __restrict__ Waug,
                                            ushort* __restrict__ w1b,
                                            ushort* __restrict__ w2b) {
  const int b = blockIdx.x;
  if (b < 32768) {
    const int id = b * 256 + threadIdx.x;  // over NTOK*DIN
    const float v = x[id];
    const float d0 = fabsf(v + 1.f), d1 = fabsf(v), d2 = fabsf(v - 1.f);
    float b0 = (d0 < 1.f) ? (1.f - d0) * (1.f - d0) : 0.f;
    float b1 = (d1 < 1.f) ? (1.f - d1) * (1.f - d1) : 0.f;
    float b2 = (d2 < 1.f) ? (1.f - d2) * (1.f - d2) : 0.f;
    const float inv = 1.f / (b0 + b1 + b2 + 1e-6f);
    ushort4 o;
    o.x = f2bf(v);
    o.y = f2bf(b0 * inv);
    o.z = f2bf(b1 * inv);
    o.w = f2bf(b2 * inv);
    ((ushort4*)Aaug)[id] = o;
  } else if (b < 32768 + 4096) {
    const int id = (b - 32768) * 256 + threadIdx.x;  // over DOUT*DIN
    ushort4 o;
    o.x = f2bf(bw[id]);
    o.y = f2bf(sw[id * 3 + 0]);
    o.z = f2bf(sw[id * 3 + 1]);
    o.w = f2bf(sw[id * 3 + 2]);
    ((ushort4*)Waug)[id] = o;
  } else {
    const int id = (b - 32768 - 4096) * 256 + threadIdx.x;  // 0..65535
    if (id < SEH * DOUT) w1b[id] = f2bf(w1[id]);
    else w2b[id - SEH * DOUT] = f2bf(w2[id - SEH * DOUT]);
  }
}

#define WAITVM(N) asm volatile("s_waitcnt vmcnt(" #N ")" ::: "memory")

// Full-K GEMM: C = A[8192x4096] * B[1024x4096]^T, f32 out direct to d_out.
// 128x128 tile, 4 waves (2Mx2N, per-wave 64x64 = acc[4][4]), BK=64.
// A: double-buffered LDS (2x16KB) via global_load_lds + XOR swizzle (R10-validated).
// B: NO LDS -- direct global->register fragment loads (Waug is L2/L1-hot, 8 MB),
//    T14 issue-early double buffer: prefetch tile kt+1's 8 B-frags during kt's
//    MFMA, consume from the other named register set (all compile-time indexed).
// vmcnt ledger per wave at tile top: [A(kt)x4, Bf(kt)x8, A(kt+1)x4] -> WAITVM(12)
// drains exactly A(kt); tail tile: [A x4, Bf x8] -> WAITVM(8).
__global__ __launch_bounds__(256, 2) void gemm_ns(const ushort* __restrict__ A,
                                                  const ushort* __restrict__ B,
                                                  float* __restrict__ C) {
  __shared__ ushort As[2][128 * BK];  // 2 x 16 KB (A only)
  const int tid = threadIdx.x;
  const int wid = tid >> 6, lane = tid & 63;
  const int l16 = lane & 15, lk = lane >> 4;
  const int wm = wid >> 1, wn = wid & 1;  // 2M x 2N wave grid

  // T1: XCD chunked swizzle (512 blocks, 64 per XCD; bn inner -> A-panel reuse)
  const int g = (blockIdx.x & 7) * 64 + (blockIdx.x >> 3);
  const int bm = g >> 3;  // 0..63
  const int bn = g & 7;   // 0..7

  const ushort* Ab = A + (size_t)bm * 128 * KAUG;
  // B fragment base for this lane: row (bn*128 + wn*64 + n*16 + l16), k-chunk lk
  const ushort* Bf0 = B + (size_t)(bn * 128 + wn * 64 + l16) * KAUG + lk * 8;

  const int lrow = lane >> 3;         // 0..7
  const int lcb = (lane & 7) ^ lrow;  // inverse-swizzled source col-block (A)

  // ds_read lane constants: element idx = aBase + m*1024 + sw(k2); sw1 = sw0^32
  const int aBase = (wm * 64 + l16) * 64;
  const int sw0 = ((l16 & 4) << 3) + ((lk ^ (l16 & 3)) << 3);
  const int sw1 = sw0 ^ 32;

  f32x4 acc[4][4] = {};
  bf16x8 bA[4][2], bB[4][2];  // two named B-fragment sets (rule #20: static idx)

#define STAGE_A(kt, buf, r)                                                     \
  __builtin_amdgcn_global_load_lds(                                             \
      (const __attribute__((address_space(1))) void*)(Ab +                      \
          (size_t)((r) * 32 + wid * 8 + lrow) * KAUG + (kt) * BK + lcb * 8),    \
      (__attribute__((address_space(3))) void*)(&As[buf][((r) * 256 + wid * 64) * 8]), \
      16, 0, 0)
#define STAGE_A4(kt, buf)                                                       \
  do { STAGE_A(kt, buf, 0); STAGE_A(kt, buf, 1); STAGE_A(kt, buf, 2); STAGE_A(kt, buf, 3); } while (0)

#define BLOAD(dst, kt)                                                          \
  do {                                                                          \
    _Pragma("unroll")                                                           \
    for (int n = 0; n < 4; ++n) {                                               \
      dst[n][0] = *(const bf16x8*)(Bf0 + (size_t)n * 16 * KAUG + (kt) * BK);    \
      dst[n][1] = *(const bf16x8*)(Bf0 + (size_t)n * 16 * KAUG + (kt) * BK + 32); \
    }                                                                           \
  } while (0)

  // One K-tile: CB compute buf / NB stage buf (compile-time), BC = current
  // B-frag set (consumed), BNX = next set (prefetched for kt+1).
#define TILE(kt, CB, NB, BC, BNX)                                               \
  do {                                                                          \
    if ((kt) < NKT - 1) {                                                       \
      STAGE_A4((kt) + 1, NB);                                                   \
      WAITVM(12);                                                               \
    } else {                                                                    \
      WAITVM(8);                                                                \
    }                                                                           \
    __builtin_amdgcn_s_barrier();                                               \
    __builtin_amdgcn_sched_barrier(0);                                          \
    bf16x8 af[4][2];                                                            \
    _Pragma("unroll")                                                           \
    for (int m = 0; m < 4; ++m) {                                               \
      af[m][0] = *(const bf16x8*)&As[CB][aBase + m * 1024 + sw0];               \
      af[m][1] = *(const bf16x8*)&As[CB][aBase + m * 1024 + sw1];               \
    }                                                                           \
    if ((kt) < NKT - 1) BLOAD(BNX, (kt) + 1); /* issue-early: overlaps MFMA */  \
    __builtin_amdgcn_s_setprio(1);                                              \
    _Pragma("unroll")                                                           \
    for (int k2 = 0; k2 < 2; ++k2)                                              \
      _Pragma("unroll")                                                         \
      for (int m = 0; m < 4; ++m)                                               \
        _Pragma("unroll")                                                       \
        for (int n = 0; n < 4; ++n)                                             \
          acc[m][n] = __builtin_amdgcn_mfma_f32_16x16x32_bf16(                  \
              af[m][k2], BC[n][k2], acc[m][n], 0, 0, 0);                        \
    __builtin_amdgcn_s_setprio(0);                                              \
    __builtin_amdgcn_s_barrier();                                               \
  } while (0)

  // prologue: stage A tile 0, load B frags for tile 0
  STAGE_A4(0, 0);
  BLOAD(bA, 0);

  for (int kt2 = 0; kt2 < NKT; kt2 += 2) {
    TILE(kt2, 0, 1, bA, bB);
    TILE(kt2 + 1, 1, 0, bB, bA);
  }

  // C/D layout: col = lane&15, row = (lane>>4)*4 + reg; f32 stores (64B sectors)
  float* Cb = C + (size_t)(bm * 128 + wm * 64) * DOUT + bn * 128 + wn * 64;
#pragma unroll
  for (int m = 0; m < 4; ++m)
#pragma unroll
    for (int n = 0; n < 4; ++n)
#pragma unroll
      for (int j = 0; j < 4; ++j)
        Cb[(size_t)(m * 16 + lk * 4 + j) * DOUT + n * 16 + l16] = acc[m][n][j];
}

// Fused LayerNorm + SE (both SE matmuls on MFMA). 16 tokens/block, 4 waves.
// In-place on out (f32). Y kept f32 in LDS; weights bf16 read from L2.
__global__ __launch_bounds__(256) void ln_se_mfma(
    float* __restrict__ out,
    const float* __restrict__ ln_w, const float* __restrict__ ln_b,
    const ushort* __restrict__ w1b, const float* __restrict__ se_b1,
    const ushort* __restrict__ w2b, const float* __restrict__ se_b2) {
  __shared__ float Yl[16 * 1028];       // 16 tokens x 1024 (+4 pad) f32
  __shared__ float Hpart[4][512];       // per-wave SE1 partials (16x32)
  __shared__ unsigned Hb[256];          // H packed bf16 [16 tok][16 u32]
  const int tid = threadIdx.x;
  const int w = tid >> 6, lane = tid & 63;
  const int l16 = lane & 15, lk = lane >> 4;
  const int tok0 = blockIdx.x * 16;

  // lane owns float4 groups q*64+lane (cols (q*64+lane)*4 .. +3)
  float4 lwv[4], lbv[4];
#pragma unroll
  for (int q = 0; q < 4; ++q) {
    lwv[q] = ((const float4*)ln_w)[q * 64 + lane];
    lbv[q] = ((const float4*)ln_b)[q * 64 + lane];
  }

  for (int qt = 0; qt < 4; ++qt) {
    const int tl = w * 4 + qt;
    const float4* r0 = (const float4*)(out + (size_t)(tok0 + tl) * DOUT);
    float4 v[4];
#pragma unroll
    for (int q = 0; q < 4; ++q) v[q] = r0[q * 64 + lane];
    float s = 0.f, ss = 0.f;
#pragma unroll
    for (int q = 0; q < 4; ++q) {
      s += v[q].x + v[q].y + v[q].z + v[q].w;
      ss += v[q].x * v[q].x + v[q].y * v[q].y + v[q].z * v[q].z + v[q].w * v[q].w;
    }
#pragma unroll
    for (int m = 32; m; m >>= 1) { s += __shfl_xor(s, m); ss += __shfl_xor(ss, m); }
    const float mu = s * (1.f / (float)DOUT);
    const float inv = rsqrtf(ss * (1.f / (float)DOUT) - mu * mu + 1e-5f);
#pragma unroll
    for (int q = 0; q < 4; ++q) {
      float4 yv;
      yv.x = (v[q].x - mu) * inv * lwv[q].x + lbv[q].x;
      yv.y = (v[q].y - mu) * inv * lwv[q].y + lbv[q].y;
      yv.z = (v[q].z - mu) * inv * lwv[q].z + lbv[q].z;
      yv.w = (v[q].w - mu) * inv * lwv[q].w + lbv[q].w;
      *(float4*)&Yl[tl * 1028 + (q * 64 + lane) * 4] = yv;
    }
  }
  __syncthreads();

  // SE1: H[16 tok][32 hid] = Y[16][1024] @ w1^T. K split across waves (256 each).
  f32x4 acc1[2] = {};
#pragma unroll
  for (int s = 0; s < 8; ++s) {
    const int ks = w * 8 + s;
    const int k = ks * 32 + lk * 8;
    const float* yp = &Yl[l16 * 1028 + k];
    const f32x4 q0 = *(const f32x4*)yp;
    const f32x4 q1 = *(const f32x4*)(yp + 4);
    bf16x8 af;
    af[0] = (__bf16)q0[0]; af[1] = (__bf16)q0[1];
    af[2] = (__bf16)q0[2]; af[3] = (__bf16)q0[3];
    af[4] = (__bf16)q1[0]; af[5] = (__bf16)q1[1];
    af[6] = (__bf16)q1[2]; af[7] = (__bf16)q1[3];
#pragma unroll
    for (int nt = 0; nt < 2; ++nt) {
      const bf16x8 bf = *(const bf16x8*)(w1b + (nt * 16 + l16) * 1024 + ks * 32 + lk * 8);
      acc1[nt] = __builtin_amdgcn_mfma_f32_16x16x32_bf16(af, bf, acc1[nt], 0, 0, 0);
    }
  }
#pragma unroll
  for (int nt = 0; nt < 2; ++nt)
#pragma unroll
    for (int j = 0; j < 4; ++j)
      Hpart[w][(lk * 4 + j) * 32 + nt * 16 + l16] = acc1[nt][j];
  __syncthreads();

  {
    const int e2 = tid * 2;
    float h0 = Hpart[0][e2] + Hpart[1][e2] + Hpart[2][e2] + Hpart[3][e2];
    float h1 = Hpart[0][e2 + 1] + Hpart[1][e2 + 1] + Hpart[2][e2 + 1] + Hpart[3][e2 + 1];
    h0 = fmaxf(h0 + se_b1[e2 & 31], 0.f);
    h1 = fmaxf(h1 + se_b1[(e2 & 31) + 1], 0.f);
    Hb[tid] = (unsigned)f2bf(h0) | ((unsigned)f2bf(h1) << 16);
  }
  __syncthreads();

  // SE2: G[16 tok][1024] = H[16][32] @ w2^T, N split across waves (256 each).
  union { uint4 u; bf16x8 v; } ha;
  ha.u = *(const uint4*)&Hb[l16 * 16 + lk * 4];
  const int nbase = w * 256;
#pragma unroll
  for (int nt = 0; nt < 16; ++nt) {
    const int col = nbase + nt * 16 + l16;
    const bf16x8 bf = *(const bf16x8*)(w2b + col * 32 + lk * 8);
    f32x4 gz = {0.f, 0.f, 0.f, 0.f};
    gz = __builtin_amdgcn_mfma_f32_16x16x32_bf16(ha.v, bf, gz, 0, 0, 0);
    const float b2 = se_b2[col];
#pragma unroll
    for (int j = 0; j < 4; ++j) {
      const int tl = lk * 4 + j;
      const float sg = 1.f / (1.f + __expf(-(gz[j] + b2)));
      out[(size_t)(tok0 + tl) * DOUT + col] = Yl[tl * 1028 + col] * sg;
    }
  }
}

extern "C" void kernel_launch(void* const* d_in, const int* in_sizes, int n_in,
                              void* d_out, int out_size, void* d_ws, size_t ws_size,
                              hipStream_t stream) {
  const float* x = (const float*)d_in[0];
  const float* bw = (const float*)d_in[1];
  const float* sw = (const float*)d_in[2];
  const float* ln_w = (const float*)d_in[3];
  const float* ln_b = (const float*)d_in[4];
  const float* se_w1 = (const float*)d_in[5];
  const float* se_b1 = (const float*)d_in[6];
  const float* se_w2 = (const float*)d_in[7];
  const float* se_b2 = (const float*)d_in[8];
  float* out = (float*)d_out;

  ushort* Aaug = (ushort*)d_ws;                        // 64 MB
  ushort* Waug = Aaug + (size_t)NTOK * KAUG;           // 8 MB
  ushort* w1b = Waug + (size_t)DOUT * KAUG;            // 64 KB
  ushort* w2b = w1b + SEH * DOUT;                      // 64 KB

  prep<<<32768 + 4096 + 256, 256, 0, stream>>>(x, bw, sw, se_w1, se_w2,
                                               Aaug, Waug, w1b, w2b);
  gemm_ns<<<512, 256, 0, stream>>>(Aaug, Waug, out);
  ln_se_mfma<<<NTOK / 16, 256, 0, stream>>>(out, ln_w, ln_b,
                                            w1b, se_b1, w2b, se_b2);
}

// Round 13
// 107.879 us; speedup vs baseline: 1.6821x; 1.6821x over previous
//
#include <hip/hip_runtime.h>
#include <hip/hip_bf16.h>
#include <math.h>

typedef __attribute__((ext_vector_type(8))) __bf16 bf16x8;
typedef __attribute__((ext_vector_type(4))) float f32x4;

#define NTOK 8192
#define DIN 1024
#define DOUT 1024
#define KAUG 4096
#define SEH 32

#define BK 64
#define NKT (KAUG / BK)  // 64 K-tiles, no split-K

static __device__ __forceinline__ unsigned short f2bf(float f) {
  union { float f; unsigned u; } v; v.f = f;
  unsigned r = (v.u + 0x7FFFu + ((v.u >> 16) & 1u)) >> 16;
  return (unsigned short)r;
}

// Merged prep: build_aaug (32768 blocks) + pack_w (4096) + pack_se (256).
__global__ __launch_bounds__(256) void prep(const float* __restrict__ x,
                                            const float* __restrict__ bw,
                                            const float* __restrict__ sw,
                                            const float* __restrict__ w1,
                                            const float* __restrict__ w2,
                                            ushort* __restrict__ Aaug,
                                            ushort* __restrict__ Waug,
                                            ushort* __restrict__ w1b,
                                            ushort* __restrict__ w2b) {
  const int b = blockIdx.x;
  if (b < 32768) {
    const int id = b * 256 + threadIdx.x;  // over NTOK*DIN
    const float v = x[id];
    const float d0 = fabsf(v + 1.f), d1 = fabsf(v), d2 = fabsf(v - 1.f);
    float b0 = (d0 < 1.f) ? (1.f - d0) * (1.f - d0) : 0.f;
    float b1 = (d1 < 1.f) ? (1.f - d1) * (1.f - d1) : 0.f;
    float b2 = (d2 < 1.f) ? (1.f - d2) * (1.f - d2) : 0.f;
    const float inv = 1.f / (b0 + b1 + b2 + 1e-6f);
    ushort4 o;
    o.x = f2bf(v);
    o.y = f2bf(b0 * inv);
    o.z = f2bf(b1 * inv);
    o.w = f2bf(b2 * inv);
    ((ushort4*)Aaug)[id] = o;
  } else if (b < 32768 + 4096) {
    const int id = (b - 32768) * 256 + threadIdx.x;  // over DOUT*DIN
    ushort4 o;
    o.x = f2bf(bw[id]);
    o.y = f2bf(sw[id * 3 + 0]);
    o.z = f2bf(sw[id * 3 + 1]);
    o.w = f2bf(sw[id * 3 + 2]);
    ((ushort4*)Waug)[id] = o;
  } else {
    const int id = (b - 32768 - 4096) * 256 + threadIdx.x;  // 0..65535
    if (id < SEH * DOUT) w1b[id] = f2bf(w1[id]);
    else w2b[id - SEH * DOUT] = f2bf(w2[id - SEH * DOUT]);
  }
}

#define WAITVM(N) asm volatile("s_waitcnt vmcnt(" #N ")" ::: "memory")

// Full-K GEMM: C = A[8192x4096] * B[1024x4096]^T, f32 out direct to d_out.
// 128x128 tile, 4 waves (2Mx2N, per-wave 64x64 = acc[4][4]), BK=64,
// double-buffered 64KB LDS -> 2 blocks/CU. R10-validated sync skeleton:
// STAGE_ALL at tile top -> counted vmcnt(8) -> entry barrier -> compute ->
// exit barrier. This revision: NO sched_barrier (let the compiler interleave
// ds_reads under MFMAs, per m97 behavior) and k2-phased source order so the
// k2=1 reads can issue under the k2=0 MFMA batch.
__global__ __launch_bounds__(256, 2) void gemm_ns(const ushort* __restrict__ A,
                                                  const ushort* __restrict__ B,
                                                  float* __restrict__ C) {
  __shared__ ushort As[2][128 * BK];  // 2 x 16 KB
  __shared__ ushort Bs[2][128 * BK];  // 2 x 16 KB
  const int tid = threadIdx.x;
  const int wid = tid >> 6, lane = tid & 63;
  const int l16 = lane & 15, lk = lane >> 4;
  const int wm = wid >> 1, wn = wid & 1;  // 2M x 2N wave grid

  // T1: XCD chunked swizzle (512 blocks, 64 per XCD; bn inner -> A-panel reuse)
  const int g = (blockIdx.x & 7) * 64 + (blockIdx.x >> 3);
  const int bm = g >> 3;  // 0..63
  const int bn = g & 7;   // 0..7

  const ushort* Ab = A + (size_t)bm * 128 * KAUG;
  const ushort* Bb = B + (size_t)bn * 128 * KAUG;

  const int lrow = lane >> 3;         // 0..7
  const int lcb = (lane & 7) ^ lrow;  // inverse-swizzled source col-block

  // ds_read lane constants (element units): index = base + m*1024 + sw(k2)
  // physical chunk = (k2*4+lk) ^ (l16&7); sw1 = sw0 ^ 32  [verified algebra]
  const int aBase = (wm * 64 + l16) * 64;
  const int bBase = (wn * 64 + l16) * 64;
  const int sw0 = ((l16 & 4) << 3) + ((lk ^ (l16 & 3)) << 3);
  const int sw1 = sw0 ^ 32;

  f32x4 acc[4][4] = {};

#define STAGE_A(kt, buf, r)                                                     \
  __builtin_amdgcn_global_load_lds(                                             \
      (const __attribute__((address_space(1))) void*)(Ab +                      \
          (size_t)((r) * 32 + wid * 8 + lrow) * KAUG + (kt) * BK + lcb * 8),    \
      (__attribute__((address_space(3))) void*)(&As[buf][((r) * 256 + wid * 64) * 8]), \
      16, 0, 0)
#define STAGE_B(kt, buf, r)                                                     \
  __builtin_amdgcn_global_load_lds(                                             \
      (const __attribute__((address_space(1))) void*)(Bb +                      \
          (size_t)((r) * 32 + wid * 8 + lrow) * KAUG + (kt) * BK + lcb * 8),    \
      (__attribute__((address_space(3))) void*)(&Bs[buf][((r) * 256 + wid * 64) * 8]), \
      16, 0, 0)
#define STAGE_ALL(kt, buf)                                                      \
  do {                                                                          \
    STAGE_A(kt, buf, 0); STAGE_A(kt, buf, 1); STAGE_A(kt, buf, 2); STAGE_A(kt, buf, 3); \
    STAGE_B(kt, buf, 0); STAGE_B(kt, buf, 1); STAGE_B(kt, buf, 2); STAGE_B(kt, buf, 3); \
  } while (0)

  // One K-tile: CB = compute buffer (compile-time), NB = stage buffer.
  // k2-phased: reads(k2) -> MFMA(k2); compiler interleaves k2=1 reads under
  // k2=0 MFMAs (register deps only; sync structure identical to R10).
#define TILE(kt, CB, NB)                                                        \
  do {                                                                          \
    if ((kt) < NKT - 1) {                                                       \
      STAGE_ALL((kt) + 1, NB);                                                  \
      WAITVM(8);                                                                \
    } else {                                                                    \
      WAITVM(0);                                                                \
    }                                                                           \
    __builtin_amdgcn_s_barrier();                                               \
    bf16x8 af0[4], bf0[4], af1[4], bf1[4];                                      \
    _Pragma("unroll")                                                           \
    for (int m = 0; m < 4; ++m) af0[m] = *(const bf16x8*)&As[CB][aBase + m * 1024 + sw0]; \
    _Pragma("unroll")                                                           \
    for (int n = 0; n < 4; ++n) bf0[n] = *(const bf16x8*)&Bs[CB][bBase + n * 1024 + sw0]; \
    __builtin_amdgcn_s_setprio(1);                                              \
    _Pragma("unroll")                                                           \
    for (int m = 0; m < 4; ++m)                                                 \
      _Pragma("unroll")                                                         \
      for (int n = 0; n < 4; ++n)                                               \
        acc[m][n] = __builtin_amdgcn_mfma_f32_16x16x32_bf16(                    \
            af0[m], bf0[n], acc[m][n], 0, 0, 0);                                \
    __builtin_amdgcn_s_setprio(0);                                              \
    _Pragma("unroll")                                                           \
    for (int m = 0; m < 4; ++m) af1[m] = *(const bf16x8*)&As[CB][aBase + m * 1024 + sw1]; \
    _Pragma("unroll")                                                           \
    for (int n = 0; n < 4; ++n) bf1[n] = *(const bf16x8*)&Bs[CB][bBase + n * 1024 + sw1]; \
    __builtin_amdgcn_s_setprio(1);                                              \
    _Pragma("unroll")                                                           \
    for (int m = 0; m < 4; ++m)                                                 \
      _Pragma("unroll")                                                         \
      for (int n = 0; n < 4; ++n)                                               \
        acc[m][n] = __builtin_amdgcn_mfma_f32_16x16x32_bf16(                    \
            af1[m], bf1[n], acc[m][n], 0, 0, 0);                                \
    __builtin_amdgcn_s_setprio(0);                                              \
    __builtin_amdgcn_s_barrier();                                               \
  } while (0)

  // prologue: stage tile 0 into buf 0
  STAGE_ALL(0, 0);

  for (int kt2 = 0; kt2 < NKT; kt2 += 2) {
    TILE(kt2, 0, 1);
    TILE(kt2 + 1, 1, 0);
  }

  // C/D layout: col = lane&15, row = (lane>>4)*4 + reg; f32 stores (64B sectors)
  float* Cb = C + (size_t)(bm * 128 + wm * 64) * DOUT + bn * 128 + wn * 64;
#pragma unroll
  for (int m = 0; m < 4; ++m)
#pragma unroll
    for (int n = 0; n < 4; ++n)
#pragma unroll
      for (int j = 0; j < 4; ++j)
        Cb[(size_t)(m * 16 + lk * 4 + j) * DOUT + n * 16 + l16] = acc[m][n][j];
}

// Fused LayerNorm + SE (both SE matmuls on MFMA). 16 tokens/block, 4 waves.
// In-place on out (f32). Y kept f32 in LDS; weights bf16 read from L2.
__global__ __launch_bounds__(256) void ln_se_mfma(
    float* __restrict__ out,
    const float* __restrict__ ln_w, const float* __restrict__ ln_b,
    const ushort* __restrict__ w1b, const float* __restrict__ se_b1,
    const ushort* __restrict__ w2b, const float* __restrict__ se_b2) {
  __shared__ float Yl[16 * 1028];       // 16 tokens x 1024 (+4 pad) f32
  __shared__ float Hpart[4][512];       // per-wave SE1 partials (16x32)
  __shared__ unsigned Hb[256];          // H packed bf16 [16 tok][16 u32]
  const int tid = threadIdx.x;
  const int w = tid >> 6, lane = tid & 63;
  const int l16 = lane & 15, lk = lane >> 4;
  const int tok0 = blockIdx.x * 16;

  // lane owns float4 groups q*64+lane (cols (q*64+lane)*4 .. +3)
  float4 lwv[4], lbv[4];
#pragma unroll
  for (int q = 0; q < 4; ++q) {
    lwv[q] = ((const float4*)ln_w)[q * 64 + lane];
    lbv[q] = ((const float4*)ln_b)[q * 64 + lane];
  }

  for (int qt = 0; qt < 4; ++qt) {
    const int tl = w * 4 + qt;
    const float4* r0 = (const float4*)(out + (size_t)(tok0 + tl) * DOUT);
    float4 v[4];
#pragma unroll
    for (int q = 0; q < 4; ++q) v[q] = r0[q * 64 + lane];
    float s = 0.f, ss = 0.f;
#pragma unroll
    for (int q = 0; q < 4; ++q) {
      s += v[q].x + v[q].y + v[q].z + v[q].w;
      ss += v[q].x * v[q].x + v[q].y * v[q].y + v[q].z * v[q].z + v[q].w * v[q].w;
    }
#pragma unroll
    for (int m = 32; m; m >>= 1) { s += __shfl_xor(s, m); ss += __shfl_xor(ss, m); }
    const float mu = s * (1.f / (float)DOUT);
    const float inv = rsqrtf(ss * (1.f / (float)DOUT) - mu * mu + 1e-5f);
#pragma unroll
    for (int q = 0; q < 4; ++q) {
      float4 yv;
      yv.x = (v[q].x - mu) * inv * lwv[q].x + lbv[q].x;
      yv.y = (v[q].y - mu) * inv * lwv[q].y + lbv[q].y;
      yv.z = (v[q].z - mu) * inv * lwv[q].z + lbv[q].z;
      yv.w = (v[q].w - mu) * inv * lwv[q].w + lbv[q].w;
      *(float4*)&Yl[tl * 1028 + (q * 64 + lane) * 4] = yv;
    }
  }
  __syncthreads();

  // SE1: H[16 tok][32 hid] = Y[16][1024] @ w1^T. K split across waves (256 each).
  f32x4 acc1[2] = {};
#pragma unroll
  for (int s = 0; s < 8; ++s) {
    const int ks = w * 8 + s;
    const int k = ks * 32 + lk * 8;
    const float* yp = &Yl[l16 * 1028 + k];
    const f32x4 q0 = *(const f32x4*)yp;
    const f32x4 q1 = *(const f32x4*)(yp + 4);
    bf16x8 af;
    af[0] = (__bf16)q0[0]; af[1] = (__bf16)q0[1];
    af[2] = (__bf16)q0[2]; af[3] = (__bf16)q0[3];
    af[4] = (__bf16)q1[0]; af[5] = (__bf16)q1[1];
    af[6] = (__bf16)q1[2]; af[7] = (__bf16)q1[3];
#pragma unroll
    for (int nt = 0; nt < 2; ++nt) {
      const bf16x8 bf = *(const bf16x8*)(w1b + (nt * 16 + l16) * 1024 + ks * 32 + lk * 8);
      acc1[nt] = __builtin_amdgcn_mfma_f32_16x16x32_bf16(af, bf, acc1[nt], 0, 0, 0);
    }
  }
#pragma unroll
  for (int nt = 0; nt < 2; ++nt)
#pragma unroll
    for (int j = 0; j < 4; ++j)
      Hpart[w][(lk * 4 + j) * 32 + nt * 16 + l16] = acc1[nt][j];
  __syncthreads();

  {
    const int e2 = tid * 2;
    float h0 = Hpart[0][e2] + Hpart[1][e2] + Hpart[2][e2] + Hpart[3][e2];
    float h1 = Hpart[0][e2 + 1] + Hpart[1][e2 + 1] + Hpart[2][e2 + 1] + Hpart[3][e2 + 1];
    h0 = fmaxf(h0 + se_b1[e2 & 31], 0.f);
    h1 = fmaxf(h1 + se_b1[(e2 & 31) + 1], 0.f);
    Hb[tid] = (unsigned)f2bf(h0) | ((unsigned)f2bf(h1) << 16);
  }
  __syncthreads();

  // SE2: G[16 tok][1024] = H[16][32] @ w2^T, N split across waves (256 each).
  union { uint4 u; bf16x8 v; } ha;
  ha.u = *(const uint4*)&Hb[l16 * 16 + lk * 4];
  const int nbase = w * 256;
#pragma unroll
  for (int nt = 0; nt < 16; ++nt) {
    const int col = nbase + nt * 16 + l16;
    const bf16x8 bf = *(const bf16x8*)(w2b + col * 32 + lk * 8);
    f32x4 gz = {0.f, 0.f, 0.f, 0.f};
    gz = __builtin_amdgcn_mfma_f32_16x16x32_bf16(ha.v, bf, gz, 0, 0, 0);
    const float b2 = se_b2[col];
#pragma unroll
    for (int j = 0; j < 4; ++j) {
      const int tl = lk * 4 + j;
      const float sg = 1.f / (1.f + __expf(-(gz[j] + b2)));
      out[(size_t)(tok0 + tl) * DOUT + col] = Yl[tl * 1028 + col] * sg;
    }
  }
}

extern "C" void kernel_launch(void* const* d_in, const int* in_sizes, int n_in,
                              void* d_out, int out_size, void* d_ws, size_t ws_size,
                              hipStream_t stream) {
  const float* x = (const float*)d_in[0];
  const float* bw = (const float*)d_in[1];
  const float* sw = (const float*)d_in[2];
  const float* ln_w = (const float*)d_in[3];
  const float* ln_b = (const float*)d_in[4];
  const float* se_w1 = (const float*)d_in[5];
  const float* se_b1 = (const float*)d_in[6];
  const float* se_w2 = (const float*)d_in[7];
  const float* se_b2 = (const float*)d_in[8];
  float* out = (float*)d_out;

  ushort* Aaug = (ushort*)d_ws;                        // 64 MB
  ushort* Waug = Aaug + (size_t)NTOK * KAUG;           // 8 MB
  ushort* w1b = Waug + (size_t)DOUT * KAUG;            // 64 KB
  ushort* w2b = w1b + SEH * DOUT;                      // 64 KB

  prep<<<32768 + 4096 + 256, 256, 0, stream>>>(x, bw, sw, se_w1, se_w2,
                                               Aaug, Waug, w1b, w2b);
  gemm_ns<<<512, 256, 0, stream>>>(Aaug, Waug, out);
  ln_se_mfma<<<NTOK / 16, 256, 0, stream>>>(out, ln_w, ln_b,
                                            w1b, se_b1, w2b, se_b2);
}